// Round 1
// baseline (301.277 us; speedup 1.0000x reference)
//
#include <hip/hip_runtime.h>

#define L_LEN 262144
#define KSZ 257
#define BLK 256
#define R 16
#define TILE (BLK * R)       // 4096 outputs per block
#define HALO (KSZ - 1)       // 256
#define LDSN (TILE + HALO)   // 4352 floats

// ---------------- dense conv1d, same padding (cross-correlation) -------------
__global__ __launch_bounds__(BLK) void conv_kernel(const float* __restrict__ in,
                                                   const float* __restrict__ w,
                                                   float* __restrict__ out) {
    __shared__ float lx[LDSN];
    const int t = threadIdx.x;
    const int tilesPerRow = L_LEN / TILE;           // 64
    const int sample = blockIdx.x / tilesPerRow;
    const int tile   = blockIdx.x % tilesPerRow;
    const float* xrow = in  + (size_t)sample * L_LEN;
    float*       orow = out + (size_t)sample * L_LEN;
    const int tstart = tile * TILE;
    const int gbase  = tstart - (KSZ / 2);          // -128

    // stage tile + halo into LDS (zero-fill out-of-range); gbase ≡ 0 mod 4
    for (int i4 = t; i4 < LDSN / 4; i4 += BLK) {
        const int g = gbase + i4 * 4;
        float4 v;
        if ((unsigned)g <= (unsigned)(L_LEN - 4)) {
            v = *(const float4*)(xrow + g);
        } else {
            v = make_float4(0.f, 0.f, 0.f, 0.f);
        }
        *(float4*)(lx + i4 * 4) = v;
    }
    __syncthreads();

    const int base = t * R;
    float acc[R], win[R];
#pragma unroll
    for (int r = 0; r < R; ++r) acc[r] = 0.f;
#pragma unroll
    for (int p = 0; p < R; ++p) win[p] = lx[base + p];

    // j = 0 .. 255 in chunks of R; sliding register window, static rotation
    for (int j0 = 0; j0 < KSZ - 1; j0 += R) {
#pragma unroll
        for (int jj = 0; jj < R; ++jj) {
            const float wj = w[j0 + jj];            // uniform -> scalar load
#pragma unroll
            for (int r = 0; r < R; ++r)
                acc[r] += win[(jj + r) & (R - 1)] * wj;
            win[jj] = lx[base + j0 + jj + R];       // slide window by 1
        }
    }
    // final tap j = 256: window slots hold x[base+256+p] at slot p
    const float wl = w[KSZ - 1];
#pragma unroll
    for (int r = 0; r < R; ++r) acc[r] += win[r] * wl;

#pragma unroll
    for (int r4 = 0; r4 < R; r4 += 4) {
        *(float4*)(orow + tstart + base + r4) =
            make_float4(acc[r4], acc[r4 + 1], acc[r4 + 2], acc[r4 + 3]);
    }
}

// ---------------- exact per-sample top-k |value| selection ------------------
#define NTH 1024
#define TCAP 4096

__global__ __launch_bounds__(NTH) void topk_kernel(const float* __restrict__ sim,
                                                   float* __restrict__ ext,
                                                   const int* __restrict__ kptr) {
    __shared__ unsigned hist[2048];
    __shared__ unsigned ss[NTH];
    __shared__ int tieIdx[TCAP];
    __shared__ int s_selBin, s_kk, s_tieCnt;

    const int t = threadIdx.x;
    const int b = blockIdx.x;
    const float* row  = sim + (size_t)b * L_LEN;
    float*       erow = ext + (size_t)b * L_LEN;
    const int k = kptr[0];

    unsigned prefix = 0;
    int prefshift = 31;                 // (u>>31)==0 matches all (sign masked)
    if (t == 0) s_kk = k;
    __syncthreads();

    const int binshift_arr[3] = {20, 10, 0};
    const int binbits_arr[3]  = {11, 10, 10};
    const unsigned binmask_arr[3] = {2047u, 1023u, 1023u};

    for (int rnd = 0; rnd < 3; ++rnd) {
        const int bshift = binshift_arr[rnd];
        const unsigned bmask = binmask_arr[rnd];
        hist[t] = 0u; hist[t + NTH] = 0u;
        __syncthreads();

        for (int i = t; i < L_LEN / 4; i += NTH) {
            const float4 v = *(const float4*)(row + i * 4);
            const float vv[4] = {v.x, v.y, v.z, v.w};
#pragma unroll
            for (int e = 0; e < 4; ++e) {
                const unsigned u = __float_as_uint(vv[e]) & 0x7fffffffu;
                if ((u >> prefshift) == prefix)
                    atomicAdd(&hist[(u >> bshift) & bmask], 1u);
            }
        }
        __syncthreads();

        // suffix sum over 2048 bins, 2 bins/thread (Hillis–Steele over pairs)
        const unsigned pairsum = hist[2 * t] + hist[2 * t + 1];
        ss[t] = pairsum;
        __syncthreads();
        for (int off = 1; off < NTH; off <<= 1) {
            const unsigned add = (t + off < NTH) ? ss[t + off] : 0u;
            __syncthreads();
            ss[t] += add;
            __syncthreads();
        }
        const unsigned kk = (unsigned)s_kk;
        const unsigned S_even = ss[t];                       // S[2t]
        const unsigned S_odd  = S_even - hist[2 * t];        // S[2t+1]
        const unsigned S_next = (t < NTH - 1) ? ss[t + 1] : 0u; // S[2t+2]
        __syncthreads();   // everyone has read s_kk/hist before updates
        if (S_odd >= kk && S_next < kk) { s_selBin = 2 * t + 1; s_kk = (int)(kk - S_next); }
        if (S_even >= kk && S_odd  < kk) { s_selBin = 2 * t;     s_kk = (int)(kk - S_odd); }
        __syncthreads();
        prefix = (prefix << binbits_arr[rnd]) | (unsigned)s_selBin;
        prefshift = bshift;
        __syncthreads();
    }

    const unsigned T = prefix;          // exact k-th largest abs-bits
    const int m = s_kk;                 // # ties (u==T) to select, by index
    if (t == 0) s_tieCnt = 0;
    __syncthreads();

    // write extrema: keep strictly-greater, zero the rest; collect ties
    for (int i = t; i < L_LEN / 4; i += NTH) {
        const float4 v = *(const float4*)(row + i * 4);
        const float vv[4] = {v.x, v.y, v.z, v.w};
        float o[4];
#pragma unroll
        for (int e = 0; e < 4; ++e) {
            const unsigned u = __float_as_uint(vv[e]) & 0x7fffffffu;
            o[e] = (u > T) ? vv[e] : 0.f;
            if (u == T) {
                const int p = atomicAdd(&s_tieCnt, 1);
                if (p < TCAP) tieIdx[p] = i * 4 + e;
            }
        }
        *(float4*)(erow + i * 4) = make_float4(o[0], o[1], o[2], o[3]);
    }
    __syncthreads();

    int tc = s_tieCnt; if (tc > TCAP) tc = TCAP;
    // select the m smallest-index ties (matches lax.top_k stability)
    for (int p = t; p < tc; p += NTH) {
        const int idx = tieIdx[p];
        int rank = 0;
        for (int q = 0; q < tc; ++q) rank += (tieIdx[q] < idx) ? 1 : 0;
        if (rank < m) erow[idx] = row[idx];
    }
}

// ----------------------------------------------------------------------------
extern "C" void kernel_launch(void* const* d_in, const int* in_sizes, int n_in,
                              void* d_out, int out_size, void* d_ws, size_t ws_size,
                              hipStream_t stream) {
    const float* x    = (const float*)d_in[0];
    const float* w    = (const float*)d_in[1];
    const int*   kptr = (const int*)d_in[2];
    float* out = (float*)d_out;

    const int total = in_sizes[0];            // B * L
    const int B = total / L_LEN;              // 64

    float* recon = out;
    float* sim   = out + (size_t)total;
    float* ext   = out + 2 * (size_t)total;

    const dim3 cgrid(B * (L_LEN / TILE));
    conv_kernel<<<cgrid, BLK, 0, stream>>>(x, w, sim);
    topk_kernel<<<B, NTH, 0, stream>>>(sim, ext, kptr);
    conv_kernel<<<cgrid, BLK, 0, stream>>>(ext, w, recon);
}